// Round 9
// baseline (36.760 us; speedup 1.0000x reference)
//
#include <hip/hip_runtime.h>
#include <hip/hip_bf16.h>
#include <math.h>

#define KN 8192
#define DEG 32
#define EE (KN*DEG)
#define NPW 4          // nodes per wave
#define NBUF 2384      // floats per LDS staging buffer

// VAR = float32(10^(-19.9) * 5000000 / 10)
#define VAR_F 6.294627058970831e-15f

typedef __attribute__((ext_vector_type(8)))  short bf16x8;
typedef __attribute__((ext_vector_type(16))) float f32x16;

static __device__ __forceinline__ short bf_hi(float f) {
    __hip_bfloat16 h = __float2bfloat16(f);
    return __builtin_bit_cast(short, h);
}
static __device__ __forceinline__ float bf_f(short s) {
    __hip_bfloat16 h = __builtin_bit_cast(__hip_bfloat16, s);
    return __bfloat162float(h);
}

// async global->LDS DMA: dest = uniform lds base + lane*size, src per-lane.
static __device__ __forceinline__ void gl16(const float* src, float* lds) {
    __builtin_amdgcn_global_load_lds(
        (const __attribute__((address_space(1))) void*)src,
        (__attribute__((address_space(3))) void*)lds, 16, 0, 0);
}
static __device__ __forceinline__ void gl4(const float* src, float* lds) {
    __builtin_amdgcn_global_load_lds(
        (const __attribute__((address_space(1))) void*)src,
        (__attribute__((address_space(3))) void*)lds, 4, 0, 0);
}

// LDS buffer layout (float offsets)
#define O_WM1 0
#define O_WM2 320
#define O_WU1 1344
#define O_WU2 2000
#define O_WH1 2128
#define O_BM1 2256
#define O_BM2 2288
#define O_BU1 2320
#define O_BU2 2336
#define O_BH1 2344
#define O_WH2 2360
#define O_BH2 2376

// Kernel 1: fused 3x conv + head + H-row gather. ONE wave per block; each
// wave handles 4 consecutive nodes. Weights stream via global_load_lds into
// a 2x9.5KB LDS double-buffer: stage(n+2) is issued right after compute(n)
// frees its buffer, so HBM stays busy across node boundaries without any
// extra VGPR cost (R7's failure mode). Compute arithmetic identical to R8:
// msg GEMM via mfma_f32_32x32x16_bf16, 3-term hi/lo split (~fp32 precision).
// All LDS wave-private -> no barriers.
__global__ __launch_bounds__(64, 2) void mpnn_fused(
    const float* __restrict__ x,
    const float* __restrict__ edge_attr,
    const float* __restrict__ H,
    const int* __restrict__ edge_index,
    const float* __restrict__ Wm1, const float* __restrict__ bm1,
    const float* __restrict__ Wm2, const float* __restrict__ bm2,
    const float* __restrict__ Wu1, const float* __restrict__ bu1,
    const float* __restrict__ Wu2, const float* __restrict__ bu2,
    const float* __restrict__ Wh1, const float* __restrict__ bh1,
    const float* __restrict__ Wh2, const float* __restrict__ bh2,
    float* __restrict__ p_ws, float* __restrict__ valid_ws,
    float* __restrict__ hv_ws)
{
    __shared__ __align__(16) float lbuf[2][NBUF];
    __shared__ __align__(16) float c_lds[32];
    __shared__ float xt[44];    // [0..8]=x, [9..40]=aggr
    __shared__ float ubuf[16];

    const int lane = threadIdx.x;
    const int col  = lane & 31;
    const int g    = lane >> 5;
    const int m    = lane & 15;
    const int dg   = lane >> 4;      // 0..3
    const int o    = lane & 7;
    const int mg   = lane >> 3;      // 0..7
    const int k0   = blockIdx.x * NPW;
    const int* dstp = edge_index + EE;

    auto stage = [&](int k, float* B) {
        const float* wm1p = Wm1 + (size_t)k*320;
        gl16(wm1p + lane*4, B + O_WM1);
        if (lane < 16) gl16(wm1p + 256 + lane*4, B + O_WM1 + 256);
        const float* wm2p = Wm2 + (size_t)k*1024;
        gl16(wm2p +       lane*4, B + O_WM2);
        gl16(wm2p + 256 + lane*4, B + O_WM2 + 256);
        gl16(wm2p + 512 + lane*4, B + O_WM2 + 512);
        gl16(wm2p + 768 + lane*4, B + O_WM2 + 768);
        const float* wu1p = Wu1 + (size_t)k*656;
        gl16(wu1p +       lane*4, B + O_WU1);
        gl16(wu1p + 256 + lane*4, B + O_WU1 + 256);
        if (lane < 36) gl16(wu1p + 512 + lane*4, B + O_WU1 + 512);
        if (lane < 32) gl16(Wu2 + (size_t)k*128 + lane*4, B + O_WU2);
        if (lane < 32) gl16(Wh1 + (size_t)k*128 + lane*4, B + O_WH1);
        if (lane < 8)  gl16(bm1 + (size_t)k*32  + lane*4, B + O_BM1);
        if (lane < 8)  gl16(bm2 + (size_t)k*32  + lane*4, B + O_BM2);
        if (lane < 4)  gl16(bu1 + (size_t)k*16  + lane*4, B + O_BU1);
        if (lane < 2)  gl16(bu2 + (size_t)k*8   + lane*4, B + O_BU2);
        if (lane < 4)  gl16(bh1 + (size_t)k*16  + lane*4, B + O_BH1);
        if (lane < 4)  gl16(Wh2 + (size_t)k*16  + lane*4, B + O_WH2);
        if (lane < 1)  gl4 (bh2 + k, B + O_BH2);
    };

    auto compute = [&](int k, const float* B, float a_e, float xval,
                       float Hv, float Hd) {
        if (lane < 9) xt[lane] = xval;

        // ---- LDS -> register weight fill (R8 layouts) ----
        float wm1v[5];
        #pragma unroll
        for (int t = 0; t < 5; ++t) wm1v[t] = B[O_WM1 + t*64 + lane];

        float w9v[16];
        {
            const float* w9p = B + O_WM1 + 288;
            float4 wa = *(const float4*)(w9p + g*8);
            float4 wb = *(const float4*)(w9p + g*8 + 4);
            float4 wc = *(const float4*)(w9p + 16 + g*8);
            float4 wd = *(const float4*)(w9p + 16 + g*8 + 4);
            w9v[0]=wa.x;  w9v[1]=wa.y;  w9v[2]=wa.z;  w9v[3]=wa.w;
            w9v[4]=wb.x;  w9v[5]=wb.y;  w9v[6]=wb.z;  w9v[7]=wb.w;
            w9v[8]=wc.x;  w9v[9]=wc.y;  w9v[10]=wc.z; w9v[11]=wc.w;
            w9v[12]=wd.x; w9v[13]=wd.y; w9v[14]=wd.z; w9v[15]=wd.w;
        }

        bf16x8 Bhi[2], Blo[2];
        #pragma unroll
        for (int s = 0; s < 2; ++s) {
            #pragma unroll
            for (int i = 0; i < 8; ++i) {
                float wv = B[O_WM2 + (s*16 + g*8 + i)*32 + col];
                short h = bf_hi(wv);
                Bhi[s][i] = h;
                Blo[s][i] = bf_hi(wv - bf_f(h));
            }
        }

        const float bm1_i = B[O_BM1 + col];
        const float bm2_i = B[O_BM2 + col];

        float wu1v[10];
        #pragma unroll
        for (int t = 0; t < 10; ++t) wu1v[t] = B[O_WU1 + t*64 + lane];
        float wu1t = (lane < 16) ? B[O_WU1 + 640 + lane] : 0.f;
        const float bu1_m = B[O_BU1 + m];

        const float wu2a  = B[O_WU2 + (mg*2+0)*8 + o];
        const float wu2b  = B[O_WU2 + (mg*2+1)*8 + o];
        const float bu2_o = B[O_BU2 + o];

        float wh1v[2];
        #pragma unroll
        for (int t = 0; t < 2; ++t) wh1v[t] = B[O_WH1 + t*64 + lane];
        const float bh1_m = B[O_BH1 + m];
        const float wh2_m = B[O_WH2 + m];
        const float bh2_k = B[O_BH2];

        // ---- 3x conv ----
        for (int it = 0; it < 3; ++it) {
            float cpart = 0.f;
            #pragma unroll
            for (int t = 0; t < 4; ++t) cpart = fmaf(xt[2*t + g], wm1v[t], cpart);
            if (g == 0) cpart = fmaf(xt[8], wm1v[4], cpart);
            float c = bm1_i + cpart + __shfl_xor(cpart, 32);
            if (g == 0) c_lds[col] = c;

            const float4* cb = (const float4*)c_lds;
            float4 q0 = cb[g*2 + 0];
            float4 q1 = cb[g*2 + 1];
            float4 q2 = cb[4 + g*2 + 0];
            float4 q3 = cb[4 + g*2 + 1];
            float cv[16] = {q0.x,q0.y,q0.z,q0.w, q1.x,q1.y,q1.z,q1.w,
                            q2.x,q2.y,q2.z,q2.w, q3.x,q3.y,q3.z,q3.w};
            bf16x8 Ahi[2], Alo[2];
            #pragma unroll
            for (int s = 0; s < 2; ++s) {
                #pragma unroll
                for (int i = 0; i < 8; ++i) {
                    int t = s*8 + i;
                    float hv = fmaxf(fmaf(a_e, w9v[t], cv[t]), 0.f);
                    short h = bf_hi(hv);
                    Ahi[s][i] = h;
                    Alo[s][i] = bf_hi(hv - bf_f(h));
                }
            }

            f32x16 acc;
            #pragma unroll
            for (int rr = 0; rr < 16; ++rr) acc[rr] = 0.f;
            #pragma unroll
            for (int s = 0; s < 2; ++s) {
                acc = __builtin_amdgcn_mfma_f32_32x32x16_bf16(Ahi[s], Bhi[s], acc, 0, 0, 0);
                acc = __builtin_amdgcn_mfma_f32_32x32x16_bf16(Ahi[s], Blo[s], acc, 0, 0, 0);
                acc = __builtin_amdgcn_mfma_f32_32x32x16_bf16(Alo[s], Bhi[s], acc, 0, 0, 0);
            }

            float ag = 0.f;
            #pragma unroll
            for (int rr = 0; rr < 16; ++rr) ag += fmaxf(acc[rr] + bm2_i, 0.f);
            ag += __shfl_xor(ag, 32);
            if (g == 0) xt[9 + col] = ag;

            float up = 0.f;
            #pragma unroll
            for (int t = 0; t < 10; ++t) up = fmaf(xt[4*t + dg], wu1v[t], up);
            up = fmaf(xt[40], wu1t, up);
            up += __shfl_xor(up, 16);
            up += __shfl_xor(up, 32);
            float u = fmaxf(up + bu1_m, 0.f);
            if (lane < 16) ubuf[lane] = u;

            float cp = wu2a * ubuf[mg*2] + wu2b * ubuf[mg*2 + 1];
            cp += __shfl_xor(cp, 8);
            cp += __shfl_xor(cp, 16);
            cp += __shfl_xor(cp, 32);
            float comb = fmaxf(cp + bu2_o, 0.f);
            if (lane < 8) xt[1 + lane] = comb;
        }

        // ---- head ----
        float hp = fmaf(xt[1 + dg], wh1v[0], 0.f);
        hp = fmaf(xt[1 + 4 + dg], wh1v[1], hp);
        hp += __shfl_xor(hp, 16);
        hp += __shfl_xor(hp, 32);
        float hh = fmaxf(hp + bh1_m, 0.f);
        float pp = hh * wh2_m;
        pp += __shfl_xor(pp, 1);
        pp += __shfl_xor(pp, 2);
        pp += __shfl_xor(pp, 4);
        pp += __shfl_xor(pp, 8);
        float z = pp + bh2_k;
        float p = 1.f / (1.f + expf(-z));

        if (g == 0) hv_ws[k*DEG + col] = Hv;   // consumed late: chain hidden
        if (lane == 0) {
            p_ws[k] = p;
            valid_ws[k] = p * Hd;
        }
    };

    // ---- prologue: per-node small register loads + gather chain ----
    int dvv[NPW]; float Hdd[NPW], aev[NPW], xv[NPW];
    #pragma unroll
    for (int n = 0; n < NPW; ++n) {
        int kk = k0 + n;
        dvv[n] = dstp[kk*DEG + col];
        Hdd[n] = H[(size_t)kk*KN + kk];
        aev[n] = edge_attr[kk*32 + col];
        xv[n]  = (lane < 9) ? x[(size_t)kk*9 + lane] : 0.f;
    }

    stage(k0 + 0, lbuf[0]);

    float Hvv[NPW];
    #pragma unroll
    for (int n = 0; n < NPW; ++n)
        Hvv[n] = H[(size_t)(k0 + n)*KN + dvv[n]];

    stage(k0 + 1, lbuf[1]);

    compute(k0 + 0, lbuf[0], aev[0], xv[0], Hvv[0], Hdd[0]);
    __builtin_amdgcn_sched_barrier(0);
    stage(k0 + 2, lbuf[0]);                 // refill freed buffer
    compute(k0 + 1, lbuf[1], aev[1], xv[1], Hvv[1], Hdd[1]);
    __builtin_amdgcn_sched_barrier(0);
    stage(k0 + 3, lbuf[1]);
    compute(k0 + 2, lbuf[0], aev[2], xv[2], Hvv[2], Hdd[2]);
    compute(k0 + 3, lbuf[1], aev[3], xv[3], Hvv[3], Hdd[3]);
}

// Kernel 2b: interference reduce from compact buffers, vectorized.
// 8 lanes per node, 4 edges per lane via int4/float4; 32 nodes per block.
__global__ __launch_bounds__(256) void mpnn_interf(
    const int* __restrict__ edge_index,
    const float* __restrict__ p_ws,
    const float* __restrict__ valid_ws,
    const float* __restrict__ hv_ws,
    float* __restrict__ out)
{
    const int tid = threadIdx.x;
    const int s   = blockIdx.x * 32 + (tid >> 3);
    const int e4  = tid & 7;
    const int* dstp = edge_index + EE;

    int4   d4 = ((const int4*)  (dstp  + s*DEG))[e4];
    float4 h4 = ((const float4*)(hv_ws + s*DEG))[e4];
    float part = p_ws[d4.x] * h4.x + p_ws[d4.y] * h4.y
               + p_ws[d4.z] * h4.z + p_ws[d4.w] * h4.w;
    part += __shfl_xor(part, 1);
    part += __shfl_xor(part, 2);
    part += __shfl_xor(part, 4);
    if (e4 == 0) {
        float interf = part + VAR_F;
        out[s] = -log1pf(valid_ws[s] / interf) * 1.4426950408889634f;
    }
}

extern "C" void kernel_launch(void* const* d_in, const int* in_sizes, int n_in,
                              void* d_out, int out_size, void* d_ws, size_t ws_size,
                              hipStream_t stream) {
    const float* x         = (const float*)d_in[0];
    const float* edge_attr = (const float*)d_in[1];
    const float* H         = (const float*)d_in[2];
    const int*   edge_idx  = (const int*)  d_in[3];
    const float* Wm1 = (const float*)d_in[4];
    const float* bm1 = (const float*)d_in[5];
    const float* Wm2 = (const float*)d_in[6];
    const float* bm2 = (const float*)d_in[7];
    const float* Wu1 = (const float*)d_in[8];
    const float* bu1 = (const float*)d_in[9];
    const float* Wu2 = (const float*)d_in[10];
    const float* bu2 = (const float*)d_in[11];
    const float* Wh1 = (const float*)d_in[12];
    const float* bh1 = (const float*)d_in[13];
    const float* Wh2 = (const float*)d_in[14];
    const float* bh2 = (const float*)d_in[15];
    float* out = (float*)d_out;

    float* p_ws     = (float*)d_ws;            // KN
    float* valid_ws = p_ws + KN;               // 2*KN (valid + spare)
    float* hv_ws    = valid_ws + 2*KN;         // KN*DEG

    mpnn_fused<<<KN/NPW, 64, 0, stream>>>(x, edge_attr, H, edge_idx,
                                          Wm1, bm1, Wm2, bm2,
                                          Wu1, bu1, Wu2, bu2, Wh1, bh1, Wh2, bh2,
                                          p_ws, valid_ws, hv_ws);
    mpnn_interf<<<KN/32, 256, 0, stream>>>(edge_idx, p_ws, valid_ws,
                                           hv_ws, out);
}

// Round 10
// 35.875 us; speedup vs baseline: 1.0247x; 1.0247x over previous
//
#include <hip/hip_runtime.h>
#include <hip/hip_bf16.h>
#include <math.h>

#define KN 8192
#define DEG 32
#define EE (KN*DEG)

// VAR = float32(10^(-19.9) * 5000000 / 10)
#define VAR_F 6.294627058970831e-15f

typedef __attribute__((ext_vector_type(8)))  short bf16x8;
typedef __attribute__((ext_vector_type(16))) float f32x16;

static __device__ __forceinline__ short bf_hi(float f) {
    __hip_bfloat16 h = __float2bfloat16(f);
    return __builtin_bit_cast(short, h);
}
static __device__ __forceinline__ float bf_f(short s) {
    __hip_bfloat16 h = __builtin_bit_cast(__hip_bfloat16, s);
    return __bfloat162float(h);
}

// async global->LDS DMA: dest = wave-uniform base + lane*16, src per-lane.
static __device__ __forceinline__ void gl16(const float* src, float* lds) {
    __builtin_amdgcn_global_load_lds(
        (const __attribute__((address_space(1))) void*)src,
        (__attribute__((address_space(3))) void*)lds, 16, 0, 0);
}

// Kernel 1: fused 3x conv + head + H-row gather. ONE wave per block; each
// wave handles 2 consecutive nodes. Wm2 (largest array) streams via
// global_load_lds into two DISTINCT __shared__ buffers (8.2KB/block so 16
// blocks/CU stay resident -- R9's occupancy mistake fixed); node1's DMA
// stays in flight under node0's compute. wm1/wu1 for node1 prefetched into
// 15 spare VGPRs. Everything else identical to R8 (verified arithmetic):
// msg GEMM via mfma_f32_32x32x16_bf16, 3-term hi/lo split (~fp32 precision).
// All LDS wave-private -> no barriers.
__global__ __launch_bounds__(64, 4) void mpnn_fused(
    const float* __restrict__ x,
    const float* __restrict__ edge_attr,
    const float* __restrict__ H,
    const int* __restrict__ edge_index,
    const float* __restrict__ Wm1, const float* __restrict__ bm1,
    const float* __restrict__ Wm2, const float* __restrict__ bm2,
    const float* __restrict__ Wu1, const float* __restrict__ bu1,
    const float* __restrict__ Wu2, const float* __restrict__ bu2,
    const float* __restrict__ Wh1, const float* __restrict__ bh1,
    const float* __restrict__ Wh2, const float* __restrict__ bh2,
    float* __restrict__ p_ws, float* __restrict__ valid_ws,
    float* __restrict__ hv_ws)
{
    __shared__ __align__(16) float LB0[1024];   // Wm2 node 0
    __shared__ __align__(16) float LB1[1024];   // Wm2 node 1
    __shared__ __align__(16) float c_lds[32];
    __shared__ float xt[44];    // [0..8]=x, [9..40]=aggr
    __shared__ float ubuf[16];

    const int lane = threadIdx.x;
    const int col  = lane & 31;
    const int g    = lane >> 5;
    const int m    = lane & 15;
    const int dg   = lane >> 4;      // 0..3
    const int o    = lane & 7;
    const int mg   = lane >> 3;      // 0..7
    const int k0   = blockIdx.x * 2;
    const int* dstp = edge_index + EE;

    // ---- upfront small per-node loads ----
    const int   dv0 = dstp[k0*DEG + col];
    const int   dv1 = dstp[(k0+1)*DEG + col];
    const float Hd0 = H[(size_t)k0*KN + k0];
    const float Hd1 = H[(size_t)(k0+1)*KN + (k0+1)];
    const float ae0 = edge_attr[k0*32 + col];
    const float ae1 = edge_attr[(k0+1)*32 + col];
    const float xv0 = (lane < 9) ? x[(size_t)k0*9 + lane] : 0.f;
    const float xv1 = (lane < 9) ? x[(size_t)(k0+1)*9 + lane] : 0.f;

    // ---- async-stage Wm2 for both nodes ----
    {
        const float* wp = Wm2 + (size_t)k0*1024;
        gl16(wp +       lane*4, LB0);
        gl16(wp + 256 + lane*4, LB0 + 256);
        gl16(wp + 512 + lane*4, LB0 + 512);
        gl16(wp + 768 + lane*4, LB0 + 768);
        const float* wq = wp + 1024;
        gl16(wq +       lane*4, LB1);
        gl16(wq + 256 + lane*4, LB1 + 256);
        gl16(wq + 512 + lane*4, LB1 + 512);
        gl16(wq + 768 + lane*4, LB1 + 768);
    }

    // ---- register prefetch of both nodes' big flat arrays (15 regs/node) ----
    float wm1vA[5], wm1vB[5];
    #pragma unroll
    for (int t = 0; t < 5; ++t) {
        wm1vA[t] = Wm1[(size_t)k0*320 + t*64 + lane];
        wm1vB[t] = Wm1[(size_t)(k0+1)*320 + t*64 + lane];
    }
    float wu1vA[10], wu1vB[10];
    #pragma unroll
    for (int t = 0; t < 10; ++t) {
        wu1vA[t] = Wu1[(size_t)k0*656 + t*64 + lane];
        wu1vB[t] = Wu1[(size_t)(k0+1)*656 + t*64 + lane];
    }

    auto compute = [&](int k, const float* WB, const float* wm1v,
                       const float* wu1v, float a_e, float xval,
                       int dvv, float Hd) {
        // issue the random H gather first; consumed only at the very end
        const float Hv = H[(size_t)k*KN + dvv];

        // remaining direct loads for this node
        float w9v[16];
        {
            const float* w9p = Wm1 + (size_t)k*320 + 288;
            float4 wa = *(const float4*)(w9p + g*8);
            float4 wb = *(const float4*)(w9p + g*8 + 4);
            float4 wc = *(const float4*)(w9p + 16 + g*8);
            float4 wd = *(const float4*)(w9p + 16 + g*8 + 4);
            w9v[0]=wa.x;  w9v[1]=wa.y;  w9v[2]=wa.z;  w9v[3]=wa.w;
            w9v[4]=wb.x;  w9v[5]=wb.y;  w9v[6]=wb.z;  w9v[7]=wb.w;
            w9v[8]=wc.x;  w9v[9]=wc.y;  w9v[10]=wc.z; w9v[11]=wc.w;
            w9v[12]=wd.x; w9v[13]=wd.y; w9v[14]=wd.z; w9v[15]=wd.w;
        }
        const float bm1_i = bm1[k*32 + col];
        const float bm2_i = bm2[k*32 + col];
        const float wu1t  = (lane < 16) ? Wu1[(size_t)k*656 + 640 + lane] : 0.f;
        const float bu1_m = bu1[k*16 + m];
        const float wu2a  = Wu2[(size_t)k*128 + (mg*2+0)*8 + o];
        const float wu2b  = Wu2[(size_t)k*128 + (mg*2+1)*8 + o];
        const float bu2_o = bu2[k*8 + o];
        const float wh1v0 = Wh1[(size_t)k*128 + lane];
        const float wh1v1 = Wh1[(size_t)k*128 + 64 + lane];
        const float bh1_m = bh1[k*16 + m];
        const float wh2_m = Wh2[k*16 + m];
        const float bh2_k = bh2[k];

        if (lane < 9) xt[lane] = xval;

        // B fragments from the staged LDS buffer (2-way bank alias = free)
        bf16x8 Bhi[2], Blo[2];
        #pragma unroll
        for (int s = 0; s < 2; ++s) {
            #pragma unroll
            for (int i = 0; i < 8; ++i) {
                float wv = WB[(s*16 + g*8 + i)*32 + col];
                short h = bf_hi(wv);
                Bhi[s][i] = h;
                Blo[s][i] = bf_hi(wv - bf_f(h));
            }
        }

        // ---- 3x conv ----
        for (int it = 0; it < 3; ++it) {
            float cpart = 0.f;
            #pragma unroll
            for (int t = 0; t < 4; ++t) cpart = fmaf(xt[2*t + g], wm1v[t], cpart);
            if (g == 0) cpart = fmaf(xt[8], wm1v[4], cpart);
            float c = bm1_i + cpart + __shfl_xor(cpart, 32);
            if (g == 0) c_lds[col] = c;

            const float4* cb = (const float4*)c_lds;
            float4 q0 = cb[g*2 + 0];
            float4 q1 = cb[g*2 + 1];
            float4 q2 = cb[4 + g*2 + 0];
            float4 q3 = cb[4 + g*2 + 1];
            float cv[16] = {q0.x,q0.y,q0.z,q0.w, q1.x,q1.y,q1.z,q1.w,
                            q2.x,q2.y,q2.z,q2.w, q3.x,q3.y,q3.z,q3.w};
            bf16x8 Ahi[2], Alo[2];
            #pragma unroll
            for (int s = 0; s < 2; ++s) {
                #pragma unroll
                for (int i = 0; i < 8; ++i) {
                    int t = s*8 + i;
                    float hv = fmaxf(fmaf(a_e, w9v[t], cv[t]), 0.f);
                    short h = bf_hi(hv);
                    Ahi[s][i] = h;
                    Alo[s][i] = bf_hi(hv - bf_f(h));
                }
            }

            f32x16 acc;
            #pragma unroll
            for (int rr = 0; rr < 16; ++rr) acc[rr] = 0.f;
            #pragma unroll
            for (int s = 0; s < 2; ++s) {
                acc = __builtin_amdgcn_mfma_f32_32x32x16_bf16(Ahi[s], Bhi[s], acc, 0, 0, 0);
                acc = __builtin_amdgcn_mfma_f32_32x32x16_bf16(Ahi[s], Blo[s], acc, 0, 0, 0);
                acc = __builtin_amdgcn_mfma_f32_32x32x16_bf16(Alo[s], Bhi[s], acc, 0, 0, 0);
            }

            float ag = 0.f;
            #pragma unroll
            for (int rr = 0; rr < 16; ++rr) ag += fmaxf(acc[rr] + bm2_i, 0.f);
            ag += __shfl_xor(ag, 32);
            if (g == 0) xt[9 + col] = ag;

            float up = 0.f;
            #pragma unroll
            for (int t = 0; t < 10; ++t) up = fmaf(xt[4*t + dg], wu1v[t], up);
            up = fmaf(xt[40], wu1t, up);
            up += __shfl_xor(up, 16);
            up += __shfl_xor(up, 32);
            float u = fmaxf(up + bu1_m, 0.f);
            if (lane < 16) ubuf[lane] = u;

            float cp = wu2a * ubuf[mg*2] + wu2b * ubuf[mg*2 + 1];
            cp += __shfl_xor(cp, 8);
            cp += __shfl_xor(cp, 16);
            cp += __shfl_xor(cp, 32);
            float comb = fmaxf(cp + bu2_o, 0.f);
            if (lane < 8) xt[1 + lane] = comb;
        }

        // ---- head ----
        float hp = fmaf(xt[1 + dg], wh1v0, 0.f);
        hp = fmaf(xt[1 + 4 + dg], wh1v1, hp);
        hp += __shfl_xor(hp, 16);
        hp += __shfl_xor(hp, 32);
        float hh = fmaxf(hp + bh1_m, 0.f);
        float pp = hh * wh2_m;
        pp += __shfl_xor(pp, 1);
        pp += __shfl_xor(pp, 2);
        pp += __shfl_xor(pp, 4);
        pp += __shfl_xor(pp, 8);
        float z = pp + bh2_k;
        float p = 1.f / (1.f + expf(-z));

        if (g == 0) hv_ws[k*DEG + col] = Hv;   // gather consumed late
        if (lane == 0) {
            p_ws[k] = p;
            valid_ws[k] = p * Hd;
        }
    };

    compute(k0,     LB0, wm1vA, wu1vA, ae0, xv0, dv0, Hd0);
    compute(k0 + 1, LB1, wm1vB, wu1vB, ae1, xv1, dv1, Hd1);
}

// Kernel 2b: interference reduce from compact buffers, vectorized.
// 8 lanes per node, 4 edges per lane via int4/float4; 32 nodes per block.
__global__ __launch_bounds__(256) void mpnn_interf(
    const int* __restrict__ edge_index,
    const float* __restrict__ p_ws,
    const float* __restrict__ valid_ws,
    const float* __restrict__ hv_ws,
    float* __restrict__ out)
{
    const int tid = threadIdx.x;
    const int s   = blockIdx.x * 32 + (tid >> 3);
    const int e4  = tid & 7;
    const int* dstp = edge_index + EE;

    int4   d4 = ((const int4*)  (dstp  + s*DEG))[e4];
    float4 h4 = ((const float4*)(hv_ws + s*DEG))[e4];
    float part = p_ws[d4.x] * h4.x + p_ws[d4.y] * h4.y
               + p_ws[d4.z] * h4.z + p_ws[d4.w] * h4.w;
    part += __shfl_xor(part, 1);
    part += __shfl_xor(part, 2);
    part += __shfl_xor(part, 4);
    if (e4 == 0) {
        float interf = part + VAR_F;
        out[s] = -log1pf(valid_ws[s] / interf) * 1.4426950408889634f;
    }
}

extern "C" void kernel_launch(void* const* d_in, const int* in_sizes, int n_in,
                              void* d_out, int out_size, void* d_ws, size_t ws_size,
                              hipStream_t stream) {
    const float* x         = (const float*)d_in[0];
    const float* edge_attr = (const float*)d_in[1];
    const float* H         = (const float*)d_in[2];
    const int*   edge_idx  = (const int*)  d_in[3];
    const float* Wm1 = (const float*)d_in[4];
    const float* bm1 = (const float*)d_in[5];
    const float* Wm2 = (const float*)d_in[6];
    const float* bm2 = (const float*)d_in[7];
    const float* Wu1 = (const float*)d_in[8];
    const float* bu1 = (const float*)d_in[9];
    const float* Wu2 = (const float*)d_in[10];
    const float* bu2 = (const float*)d_in[11];
    const float* Wh1 = (const float*)d_in[12];
    const float* bh1 = (const float*)d_in[13];
    const float* Wh2 = (const float*)d_in[14];
    const float* bh2 = (const float*)d_in[15];
    float* out = (float*)d_out;

    float* p_ws     = (float*)d_ws;            // KN
    float* valid_ws = p_ws + KN;               // KN
    float* hv_ws    = valid_ws + KN;           // KN*DEG

    mpnn_fused<<<KN/2, 64, 0, stream>>>(x, edge_attr, H, edge_idx,
                                        Wm1, bm1, Wm2, bm2,
                                        Wu1, bu1, Wu2, bu2, Wh1, bh1, Wh2, bh2,
                                        p_ws, valid_ws, hv_ws);
    mpnn_interf<<<KN/32, 256, 0, stream>>>(edge_idx, p_ws, valid_ws,
                                           hv_ws, out);
}